// Round 7
// baseline (1151.704 us; speedup 1.0000x reference)
//
#include <hip/hip_runtime.h>
#include <math.h>

#define NN 128
#define SM 129   // padded LDS stride for 128-wide f32 tiles
#define RS 132   // row-panel stride (doubles)
#define SS 17    // per-wave scratch stride (doubles)

typedef double d4 __attribute__((ext_vector_type(4)));

// ---------------------------------------------------------------------------
// K1: build symmetric-normalized Laplacian per graph
// ---------------------------------------------------------------------------
__global__ __launch_bounds__(256) void k1_laplacian(
    const int* __restrict__ src, const int* __restrict__ dst,
    int E, float* __restrict__ Lout) {
  extern __shared__ float sm1[];            // A[128*129] + dinv[128]
  float* A    = sm1;
  float* dinv = sm1 + NN * SM;
  const int g   = blockIdx.x;
  const int tid = threadIdx.x;

  for (int e = tid; e < NN * NN; e += 256) {
    int i = e >> 7, j = e & 127;
    A[i * SM + j] = 0.f;
  }
  __syncthreads();
  const int* s = src + (size_t)g * E;
  const int* d = dst + (size_t)g * E;
  for (int e = tid; e < E; e += 256) {
    int a = s[e], b = d[e];
    A[a * SM + b] = 1.f;     // benign races: all write 1.0
    A[b * SM + a] = 1.f;
  }
  __syncthreads();
  if (tid < NN) {
    float acc = 0.f;
    for (int j = 0; j < NN; ++j) acc += A[tid * SM + j];
    dinv[tid] = (acc > 0.f) ? (float)(1.0 / sqrt((double)acc)) : 0.f;
  }
  __syncthreads();
  float* Lg = Lout + (size_t)g * NN * NN;
  for (int e = tid; e < NN * NN; e += 256) {
    int i = e >> 7, j = e & 127;
    Lg[e] = ((i == j) ? 1.f : 0.f) - dinv[i] * dinv[j] * A[i * SM + j];
  }
}

// ---------------------------------------------------------------------------
// K2 (R7): register-resident blocked Gauss-Jordan.
//
// R6 post-mortem: 580us, MfmaUtil 25.7% (==MFMA arithmetic floor share),
// ~50% of time in barrier/latency stalls: 135KB LDS -> 1 block/CU, 32
// barriers/block, 1-wave-serial Pi, 2.6e7 LDS conflicts on the f64 A array.
//
// R7: A lives in MFMA ACCUMULATOR REGISTERS (wave w owns rows 16w..16w+15 as
// 8 d4 tiles = 64 regs; natural AGPR home, no VALU tax -- unlike R2/R3 where
// a VALU-owned fp64 array hit AGPR-shuffle/scratch). LDS keeps only:
//   Rp  [16][132] f64  row panel (wave t's old band), published once/step
//   Sc  8 x [16][17] f64 per-wave scratch for D-layout <-> A-layout transform
// aliased over the phase1-3 f32 tile. LDS 65KB -> 2 blocks/CU; barriers
// 4/step -> 2/step; Pi inverted REDUNDANTLY by all 8 waves (no serial phase).
//
// GJ step t (K = rows/cols 16t..; == scalar GJ, same algebra as R6):
//   B1; all waves: Pi = inv(Rp[:,K]) via shuffles (sr[r] = Pi[4kq+r][m])
//   (c) col tile: w!=t: T[t] := old@(-Pi)  (a: own scratch, b: 4-shfl extract)
//       w==t: T[t] := Pi (scratch round-trip); scratch := new col tile
//   (d/f) unified, cb!=t: acc = (w==t ? 0 : T[cb]);
//         acc += scratch_a @ Rp_b; T[cb] = acc
//   B2 (protects Rp until all reads done)
// __launch_bounds__(512,4): 128-reg budget = 64 AGPR (T) + ~50 arch.
// ---------------------------------------------------------------------------
__global__ __launch_bounds__(512, 4) void k2_filter(
    const float* __restrict__ L, const float* __restrict__ C,
    int NF, float* __restrict__ W) {
  extern __shared__ char smraw[];
  float*  smf = (float*)smraw;                       // phase 1-3: M / P2
  double* Rp  = (double*)smraw;                      // phase 4: row panel 16x132
  double* Scd = (double*)(smraw + 16 * RS * 8);      // 8 wave scratches 16x17

  const int bid = blockIdx.x;
  const int g = bid / NF, f = bid % NF;
  const int tid = threadIdx.x;
  const int wv = tid >> 6, ln = tid & 63;
  const int m  = ln & 15, kq = ln >> 4;   // forced A/B operand coords
  double* S = Scd + wv * 16 * SS;         // own wave scratch

  double csum = 0.0;
  for (int q = 0; q < NF; ++q) { double c = (double)C[q]; csum += c * c; }
  double cn = sqrt(csum); if (cn < 1e-12) cn = 1e-12;
  const double a4 = 6.25e-6;                         // (STEP/2)^4
  const double coef = 1.4142135623730951 * a4 * ((double)C[f] / cn);
  const float  bf = (float)((double)f * 0.1);

  // --- runtime D-layout probe (layout-proof; verified working in R6) ---
  int rIdx[4], cIdx[4];
  {
    d4 z = {0.0, 0.0, 0.0, 0.0};
    d4 pr = __builtin_amdgcn_mfma_f64_16x16x4f64((double)m, 1.0, z, 0, 0, 0);
    d4 pc = __builtin_amdgcn_mfma_f64_16x16x4f64(1.0, (double)m, z, 0, 0, 0);
#pragma unroll
    for (int r = 0; r < 4; ++r) {
      rIdx[r] = ((int)(pr[r] * 0.25 + 0.5)) & 15;
      cIdx[r] = ((int)(pc[r] * 0.25 + 0.5)) & 15;
    }
  }

  // phase 1: M = L - b I  (f32 LDS)
  const float* Lg = L + (size_t)g * NN * NN;
  for (int e = tid; e < NN * NN; e += 512) {
    int i = e >> 7, j = e & 127;
    float v = Lg[e];
    if (i == j) v -= bf;
    smf[i * SM + j] = v;
  }
  __syncthreads();

  // phase 2: P2 = M @ M  (fp32 VALU, 4x8 regs/thread; proven R3-R6)
  {
    const int tr = tid >> 4;                // 0..31
    const int tc = tid & 15;
    float p2r[4][8];
#pragma unroll
    for (int v = 0; v < 4; ++v)
#pragma unroll
      for (int u = 0; u < 8; ++u) p2r[v][u] = 0.f;
    for (int k = 0; k < NN; ++k) {
      float av[4], bv[8];
#pragma unroll
      for (int v = 0; v < 4; ++v) av[v] = smf[(4 * tr + v) * SM + k];
#pragma unroll
      for (int u = 0; u < 8; ++u) bv[u] = smf[k * SM + tc + 16 * u];
#pragma unroll
      for (int v = 0; v < 4; ++v)
#pragma unroll
        for (int u = 0; u < 8; ++u) p2r[v][u] = fmaf(av[v], bv[u], p2r[v][u]);
    }
    __syncthreads();
#pragma unroll
    for (int v = 0; v < 4; ++v)
#pragma unroll
      for (int u = 0; u < 8; ++u) smf[(4 * tr + v) * SM + tc + 16 * u] = p2r[v][u];
    __syncthreads();
  }

  // phase 3: T[cb] = (P2 @ P2 + a I) row-band 16wv  -- stays in registers
  d4 T[8];
#pragma unroll
  for (int cb = 0; cb < 8; ++cb)
#pragma unroll
    for (int r = 0; r < 4; ++r)
      T[cb][r] = ((16 * wv + rIdx[r]) == (16 * cb + cIdx[r])) ? a4 : 0.0;
  for (int kc = 0; kc < 32; ++kc) {
    double a = (double)smf[(16 * wv + m) * SM + 4 * kc + kq];
#pragma unroll
    for (int cb = 0; cb < 8; ++cb) {
      double b = (double)smf[(4 * kc + kq) * SM + 16 * cb + m];
      T[cb] = __builtin_amdgcn_mfma_f64_16x16x4f64(a, b, T[cb], 0, 0, 0);
    }
  }
  __syncthreads();   // P2 reads done; f32 region dead -> Rp/Sc alias it

  // phase 4: blocked GJ, 8 steps, 2 block-barriers each
#pragma unroll
  for (int t = 0; t < 8; ++t) {
    // publish row panel (wave t's OLD band, D-layout scatter)
    if (wv == t) {
#pragma unroll
      for (int cb = 0; cb < 8; ++cb)
#pragma unroll
        for (int r = 0; r < 4; ++r)
          Rp[rIdx[r] * RS + 16 * cb + cIdx[r]] = T[cb][r];
    }
    __syncthreads();                                 // B1

    // all waves redundantly: Pi = inv(A[K][K]) via 16 shuffle-pivots
    double sr[4];
#pragma unroll
    for (int r = 0; r < 4; ++r) sr[r] = Rp[(4 * kq + r) * RS + 16 * t + m];
#pragma unroll
    for (int k = 0; k < 16; ++k) {
      const int g2 = k >> 2, rr = k & 3;
      double pv   = __shfl(sr[rr], 16 * g2 + k);
      double rowv = __shfl(sr[rr], 16 * g2 + m);
      double cv[4];
#pragma unroll
      for (int r = 0; r < 4; ++r) cv[r] = __shfl(sr[r], 16 * kq + k);
      double dp = 1.0 / pv;
#pragma unroll
      for (int r = 0; r < 4; ++r) {
        int i = 4 * kq + r;
        double nv;
        if (i == k)      nv = (m == k) ? dp : rowv * dp;
        else if (m == k) nv = -cv[r] * dp;
        else             nv = fma(-(cv[r] * dp), rowv, sr[r]);
        sr[r] = nv;
      }
    }
    // sr[r] = Pi[4kq+r][m]

    // (c) column tile K
    if (wv == t) {
      // T[t] := Pi  (scratch round-trip to reach D-layout); scratch := Pi
#pragma unroll
      for (int r = 0; r < 4; ++r) S[(4 * kq + r) * SS + m] = sr[r];
      __builtin_amdgcn_wave_barrier();
#pragma unroll
      for (int r = 0; r < 4; ++r) T[t][r] = S[rIdx[r] * SS + cIdx[r]];
    } else {
      // scatter OLD tile t -> scratch (A-layout source)
#pragma unroll
      for (int r = 0; r < 4; ++r) S[rIdx[r] * SS + cIdx[r]] = T[t][r];
      __builtin_amdgcn_wave_barrier();
      d4 nc = {0.0, 0.0, 0.0, 0.0};
#pragma unroll
      for (int kc = 0; kc < 4; ++kc) {
        double a = S[m * SS + 4 * kc + kq];
        double b0 = __shfl(sr[0], m + 16 * kc);
        double b1 = __shfl(sr[1], m + 16 * kc);
        double b2 = __shfl(sr[2], m + 16 * kc);
        double b3 = __shfl(sr[3], m + 16 * kc);
        double b = (kq == 0) ? b0 : (kq == 1) ? b1 : (kq == 2) ? b2 : b3;
        nc = __builtin_amdgcn_mfma_f64_16x16x4f64(a, -b, nc, 0, 0, 0);
      }
      T[t] = nc;
      __builtin_amdgcn_wave_barrier();
#pragma unroll
      for (int r = 0; r < 4; ++r) S[rIdx[r] * SS + cIdx[r]] = T[t][r];
      __builtin_amdgcn_wave_barrier();
    }

    // (d)/(f) unified: 7 tiles; a from own scratch (new col / Pi), b from Rp
#pragma unroll
    for (int cb = 0; cb < 8; ++cb) {
      if (cb == t) continue;
      d4 acc;
      if (wv == t) { acc[0] = 0.0; acc[1] = 0.0; acc[2] = 0.0; acc[3] = 0.0; }
      else         { acc = T[cb]; }
#pragma unroll
      for (int kc = 0; kc < 4; ++kc) {
        double a = S[m * SS + 4 * kc + kq];
        double b = Rp[(4 * kc + kq) * RS + 16 * cb + m];
        acc = __builtin_amdgcn_mfma_f64_16x16x4f64(a, b, acc, 0, 0, 0);
      }
      T[cb] = acc;
    }
    __syncthreads();                                 // B2
  }

  // phase 5: W += coef * K^{-1}
  float* Wg = W + (size_t)g * NN * NN;
#pragma unroll
  for (int cb = 0; cb < 8; ++cb)
#pragma unroll
    for (int r = 0; r < 4; ++r)
      atomicAdd(&Wg[(16 * wv + rIdx[r]) * NN + 16 * cb + cIdx[r]],
                (float)(coef * T[cb][r]));
}

// ---------------------------------------------------------------------------
// K3a: Y = X - W @ X  per (graph, d-chunk of 128); also per-chunk emb (col means)
// ---------------------------------------------------------------------------
__global__ __launch_bounds__(256, 2) void k3a_y(
    const float* __restrict__ x, const float* __restrict__ rs,
    const float* __restrict__ W, float* __restrict__ Y,
    float* __restrict__ emb, int F0, int R, int DTOT, int NCH,
    float rscale) {
  extern __shared__ float sm3[];
  float* ldsW = sm3;                 // 128*129
  float* ldsX = sm3 + NN * SM;       // 128*129
  const int bid = blockIdx.x;
  const int g = bid / NCH;
  const int c = bid % NCH;
  const int d0 = c * 128;
  const int tid = threadIdx.x, tr = tid >> 4, tc = tid & 15;

  const float* Wg = W + (size_t)g * NN * NN;
  for (int e = tid; e < NN * NN; e += 256) {
    int k = e >> 7, i = e & 127;
    ldsW[k * SM + i] = Wg[e];
  }
  const float* xg = x + (size_t)g * NN * F0;
  const float* rg = rs + (size_t)g * NN * R;
  for (int e = tid; e < NN * NN; e += 256) {
    int k = e >> 7, dl = e & 127;
    int d = d0 + dl;
    float v = 0.f;
    if (d < DTOT) v = (d < F0) ? xg[k * F0 + d] : rg[k * R + (d - F0)] * rscale;
    ldsX[k * SM + dl] = v;
  }
  __syncthreads();

  float acc[8][8];
#pragma unroll
  for (int v = 0; v < 8; ++v)
#pragma unroll
    for (int u = 0; u < 8; ++u) acc[v][u] = 0.f;
  for (int k = 0; k < NN; ++k) {
    float wvv[8], xv[8];
#pragma unroll
    for (int v = 0; v < 8; ++v) wvv[v] = ldsW[k * SM + 8 * tr + v];  // W symmetric
#pragma unroll
    for (int u = 0; u < 8; ++u) xv[u] = ldsX[k * SM + tc + 16 * u];
#pragma unroll
    for (int v = 0; v < 8; ++v)
#pragma unroll
      for (int u = 0; u < 8; ++u) acc[v][u] = fmaf(wvv[v], xv[u], acc[v][u]);
  }
  float* Yg = Y + (size_t)g * NN * 1152;
#pragma unroll
  for (int v = 0; v < 8; ++v)
#pragma unroll
    for (int u = 0; u < 8; ++u) {
      float yv = ldsX[(8 * tr + v) * SM + tc + 16 * u] - acc[v][u];
      acc[v][u] = yv;
      Yg[(8 * tr + v) * 1152 + d0 + tc + 16 * u] = yv;
    }
  __syncthreads();
  float* embp = ldsW;
#pragma unroll
  for (int u = 0; u < 8; ++u) {
    float s = 0.f;
#pragma unroll
    for (int v = 0; v < 8; ++v) s += acc[v][u];
    embp[tr * 128 + tc + 16 * u] = s;
  }
  __syncthreads();
  if (tid < 128) {
    int d = d0 + tid;
    if (d < DTOT) {
      float s = 0.f;
      for (int tt = 0; tt < 16; ++tt) s += embp[tt * 128 + tid];
      emb[(size_t)g * 1152 + d] = s * (1.f / 128.f);
    }
  }
}

// ---------------------------------------------------------------------------
// K3b: G += Ychunk @ Ychunk^T  per (graph, d-chunk), via transposed LDS tile
// ---------------------------------------------------------------------------
__global__ __launch_bounds__(256, 2) void k3b_gram(
    const float* __restrict__ Y, float* __restrict__ G,
    int DTOT, int NCH) {
  extern __shared__ float sm4[];     // Yt[128 d][132]
  const int STT = 132;
  const int bid = blockIdx.x;
  const int g = bid / NCH, c = bid % NCH, d0 = c * 128;
  const int tid = threadIdx.x, tr = tid >> 4, tc = tid & 15;
  const float* Yg = Y + (size_t)g * NN * 1152;
  for (int e = tid; e < NN * NN; e += 256) {
    int i = e >> 7, dl = e & 127;
    int d = d0 + dl;
    sm4[dl * STT + i] = (d < DTOT) ? Yg[i * 1152 + d] : 0.f;
  }
  __syncthreads();
  float gg[8][8];
#pragma unroll
  for (int v = 0; v < 8; ++v)
#pragma unroll
    for (int u = 0; u < 8; ++u) gg[v][u] = 0.f;
  for (int dl = 0; dl < 128; ++dl) {
    float av[8], bv[8];
#pragma unroll
    for (int v = 0; v < 8; ++v) av[v] = sm4[dl * STT + 8 * tr + v];
#pragma unroll
    for (int u = 0; u < 8; ++u) bv[u] = sm4[dl * STT + tc + 16 * u];
#pragma unroll
    for (int v = 0; v < 8; ++v)
#pragma unroll
      for (int u = 0; u < 8; ++u) gg[v][u] = fmaf(av[v], bv[u], gg[v][u]);
  }
  float* Gg = G + (size_t)g * NN * NN;
#pragma unroll
  for (int v = 0; v < 8; ++v)
#pragma unroll
    for (int u = 0; u < 8; ++u)
      atomicAdd(&Gg[(8 * tr + v) * NN + tc + 16 * u], gg[v][u]);
}

// ---------------------------------------------------------------------------
// K4: sp_g = -sum_ij |G_ij| / (n_i n_j) / N^2
// ---------------------------------------------------------------------------
__global__ __launch_bounds__(256) void k4_sp(const float* __restrict__ G,
                                             double* __restrict__ spt) {
  __shared__ float inr[NN];
  __shared__ double red[4];
  const int g = blockIdx.x, tid = threadIdx.x;
  const float* Gg = G + (size_t)g * NN * NN;
  if (tid < NN) {
    float n = sqrtf(fmaxf(Gg[tid * NN + tid], 0.f));
    inr[tid] = 1.f / fmaxf(n, 1e-12f);
  }
  __syncthreads();
  double s = 0.0;
  for (int e = tid; e < NN * NN; e += 256) {
    int i = e >> 7, j = e & 127;
    s += (double)(fabsf(Gg[e]) * inr[i] * inr[j]);
  }
  for (int off = 32; off; off >>= 1) s += __shfl_down(s, off);
  int wave = tid >> 6, lane = tid & 63;
  if (lane == 0) red[wave] = s;
  __syncthreads();
  if (tid == 0) spt[g] = -(red[0] + red[1] + red[2] + red[3]) / (double)(NN * NN);
}

// ---------------------------------------------------------------------------
// K5a: 64x64 pairwise-distance matrix over embeddings
// ---------------------------------------------------------------------------
__global__ __launch_bounds__(256) void k5a_cdist(const float* __restrict__ emb,
                                                 float* __restrict__ Dm, int DTOT) {
  __shared__ float red[4];
  const int i = blockIdx.x, tid = threadIdx.x;
  float ei[5];
#pragma unroll
  for (int s2 = 0; s2 < 5; ++s2) {
    int d = tid + 256 * s2;
    ei[s2] = (d < DTOT) ? emb[(size_t)i * 1152 + d] : 0.f;
  }
  for (int j = 0; j < 64; ++j) {
    float acc = 0.f;
#pragma unroll
    for (int s2 = 0; s2 < 5; ++s2) {
      int d = tid + 256 * s2;
      if (d < DTOT) {
        float df = ei[s2] - emb[(size_t)j * 1152 + d];
        acc = fmaf(df, df, acc);
      }
    }
    for (int off = 32; off; off >>= 1) acc += __shfl_down(acc, off);
    int wave = tid >> 6, lane = tid & 63;
    if (lane == 0) red[wave] = acc;
    __syncthreads();
    if (tid == 0) {
      float d2 = red[0] + red[1] + red[2] + red[3];
      Dm[i * 64 + j] = (d2 > 0.f) ? sqrtf(d2) : 0.f;
    }
    __syncthreads();
  }
}

// ---------------------------------------------------------------------------
// K5b: final scalar (single wave)
// ---------------------------------------------------------------------------
__global__ __launch_bounds__(64) void k5b_final(
    const float* __restrict__ Dm, const double* __restrict__ spt,
    const float* __restrict__ C, int NF,
    const int* __restrict__ ncls, float* __restrict__ out) {
  const int lane = threadIdx.x;
  const int nc = ncls[0];
  double spf = spt[lane] * exp(-((double)(64 - lane)) * log(64.0));
  for (int off = 32; off; off >>= 1) spf += __shfl_down(spf, off);

  double hl1 = 0.0, hl2 = 0.0;
  const double beta = 1.0 / (double)nc + 1e-13;
  for (int cc = 0; cc < nc; ++cc) {
    bool ip = (lane % nc) == cc;
    double ps = 0.0, ns = 0.0;
    for (int j = 0; j < 64; ++j) {
      double dv = (double)Dm[lane * 64 + j];
      bool jp = (j % nc) == cc;
      if (ip && jp) ps += dv;
      if (!ip && !jp) ns += dv;
    }
    for (int off = 32; off; off >>= 1) {
      ps += __shfl_down(ps, off);
      ns += __shfl_down(ns, off);
    }
    int npos = 0;
    for (int q = 0; q < 64; ++q) if (q % nc == cc) npos++;
    int nneg = 64 - npos;
    hl2 += ps / ((double)npos * (double)npos);
    hl1 += -(ns / ((double)nneg * (double)nneg)) / beta;
  }
  if (lane == 0) {
    double l1 = 0.0, l2 = 0.0;
    for (int q = 0; q < NF; ++q) { double cv = (double)C[q]; l1 += fabs(cv); l2 += cv * cv; }
    l2 = sqrt(l2); if (l2 < 1e-12) l2 = 1e-12;
    double dims = sqrt((double)NF);
    double sc = (dims - l1 / l2) / (dims - 1.0);
    out[0] = (float)(sc + hl2 + hl1 + spf);
  }
}

// ---------------------------------------------------------------------------
extern "C" void kernel_launch(void* const* d_in, const int* in_sizes, int n_in,
                              void* d_out, int out_size, void* d_ws, size_t ws_size,
                              hipStream_t stream) {
  (void)n_in; (void)out_size; (void)ws_size;
  const float* x    = (const float*)d_in[0];
  const float* rs   = (const float*)d_in[1];
  const float* C    = (const float*)d_in[2];
  const int*   esrc = (const int*)d_in[3];
  const int*   edst = (const int*)d_in[4];
  const int*   ncls = (const int*)d_in[5];
  float* out = (float*)d_out;

  const int F0   = in_sizes[0] / (64 * 128);
  const int R    = in_sizes[1] / (64 * 128);
  const int NF   = in_sizes[2];
  const int E    = in_sizes[3] / 64;
  const int DTOT = F0 + R;
  const int NCH  = (DTOT + 127) / 128;
  const float rscale = (float)(1.0 / sqrt((double)R));

  char* ws = (char*)d_ws;
  size_t off = 0;
  float*  L   = (float*)(ws + off);  off += (size_t)64 * NN * NN * 4;
  float*  W   = (float*)(ws + off);  off += (size_t)64 * NN * NN * 4;
  float*  Y   = (float*)(ws + off);  off += (size_t)64 * NN * 1152 * 4;
  float*  G   = (float*)(ws + off);  off += (size_t)64 * NN * NN * 4;
  float*  emb = (float*)(ws + off);  off += (size_t)64 * 1152 * 4;
  double* spt = (double*)(ws + off); off += (size_t)64 * 8;
  float*  Dm  = (float*)(ws + off);  off += (size_t)64 * 64 * 4;

  hipMemsetAsync(W, 0, (size_t)64 * NN * NN * 4, stream);
  hipMemsetAsync(G, 0, (size_t)64 * NN * NN * 4, stream);

  const int lds1  = (NN * SM + NN) * 4;       // 66560
  const int lds2  = NN * SM * 4;              // 66048 (phase1-3 f32; phase4 aliases 34KB)
  const int lds3a = (NN * SM) * 4 * 2;        // 132096
  const int lds3b = NN * 132 * 4;             // 67584
  hipFuncSetAttribute((const void*)k1_laplacian, hipFuncAttributeMaxDynamicSharedMemorySize, lds1);
  hipFuncSetAttribute((const void*)k2_filter,    hipFuncAttributeMaxDynamicSharedMemorySize, lds2);
  hipFuncSetAttribute((const void*)k3a_y,        hipFuncAttributeMaxDynamicSharedMemorySize, lds3a);
  hipFuncSetAttribute((const void*)k3b_gram,     hipFuncAttributeMaxDynamicSharedMemorySize, lds3b);

  k1_laplacian<<<64, 256, lds1, stream>>>(esrc, edst, E, L);
  k2_filter<<<64 * NF, 512, lds2, stream>>>(L, C, NF, W);
  k3a_y<<<64 * NCH, 256, lds3a, stream>>>(x, rs, W, Y, emb, F0, R, DTOT, NCH, rscale);
  k3b_gram<<<64 * NCH, 256, lds3b, stream>>>(Y, G, DTOT, NCH);
  k4_sp<<<64, 256, 0, stream>>>(G, spt);
  k5a_cdist<<<64, 256, 0, stream>>>(emb, Dm, DTOT);
  k5b_final<<<1, 64, 0, stream>>>(Dm, spt, C, NF, ncls, out);
}

// Round 8
// 939.567 us; speedup vs baseline: 1.2258x; 1.2258x over previous
//
#include <hip/hip_runtime.h>
#include <math.h>

#define NN 128
#define SM 129   // padded LDS stride for 128-wide f32 tiles
#define RS 132   // row-panel stride (doubles)
#define SS 17    // per-wave scratch stride (doubles)

typedef double d4 __attribute__((ext_vector_type(4)));

// ---------------------------------------------------------------------------
// K1: build symmetric-normalized Laplacian per graph
// ---------------------------------------------------------------------------
__global__ __launch_bounds__(256) void k1_laplacian(
    const int* __restrict__ src, const int* __restrict__ dst,
    int E, float* __restrict__ Lout) {
  extern __shared__ float sm1[];            // A[128*129] + dinv[128]
  float* A    = sm1;
  float* dinv = sm1 + NN * SM;
  const int g   = blockIdx.x;
  const int tid = threadIdx.x;

  for (int e = tid; e < NN * NN; e += 256) {
    int i = e >> 7, j = e & 127;
    A[i * SM + j] = 0.f;
  }
  __syncthreads();
  const int* s = src + (size_t)g * E;
  const int* d = dst + (size_t)g * E;
  for (int e = tid; e < E; e += 256) {
    int a = s[e], b = d[e];
    A[a * SM + b] = 1.f;     // benign races: all write 1.0
    A[b * SM + a] = 1.f;
  }
  __syncthreads();
  if (tid < NN) {
    float acc = 0.f;
    for (int j = 0; j < NN; ++j) acc += A[tid * SM + j];
    dinv[tid] = (acc > 0.f) ? (float)(1.0 / sqrt((double)acc)) : 0.f;
  }
  __syncthreads();
  float* Lg = Lout + (size_t)g * NN * NN;
  for (int e = tid; e < NN * NN; e += 256) {
    int i = e >> 7, j = e & 127;
    Lg[e] = ((i == j) ? 1.f : 0.f) - dinv[i] * dinv[j] * A[i * SM + j];
  }
}

// ---------------------------------------------------------------------------
// K2 (R8): register-resident blocked Gauss-Jordan, spill-proofed.
//
// R7 post-mortem: full unroll of the 8-step GJ loop let the scheduler blow
// the 128-reg budget -> T spilled to scratch (FETCH 0.6GB / WRITE 1.6GB,
// 730us). R8 fixes the code SHAPE, same algebra:
//   * t-loop is NOT unrolled (#pragma unroll 1) -> per-iter live set ~110.
//   * T[t] dynamic indexing avoided via guarded unrolled cb-loop
//     (if (cb != t) continue;) -> all T indices static.
//   * Pi inversion runs in TRANSPOSED register layout sr[r] = Pi[4r+kq][m],
//     so the column-tile MFMA B-operand is just sr[kc] (16 shuffles + 4
//     selects per step deleted).
// Wave w owns rows 16w..16w+15 of A as 8 d4 MFMA accumulators (AGPR-native).
// LDS (aliased over phase1-3 f32 tile, 66048 B total -> 2 blocks/CU):
//   Rp [16][132] f64: wave t's old row band;  Sc 8x[16][17] f64: per-wave
//   scratch for D-layout <-> row-major transforms.
// Per step: B1 (Rp publish) ... B2 (Rp protect) = 2 block barriers.
// ---------------------------------------------------------------------------
__global__ __launch_bounds__(512, 4) void k2_filter(
    const float* __restrict__ L, const float* __restrict__ C,
    int NF, float* __restrict__ W) {
  extern __shared__ char smraw[];
  float*  smf = (float*)smraw;                       // phase 1-3: M / P2
  double* Rp  = (double*)smraw;                      // phase 4: row panel 16x132
  double* Scd = (double*)(smraw + 16 * RS * 8);      // 8 wave scratches 16x17

  const int bid = blockIdx.x;
  const int g = bid / NF, f = bid % NF;
  const int tid = threadIdx.x;
  const int wv = tid >> 6, ln = tid & 63;
  const int m  = ln & 15, kq = ln >> 4;   // forced A/B operand coords
  double* S = Scd + wv * 16 * SS;         // own wave scratch

  double csum = 0.0;
  for (int q = 0; q < NF; ++q) { double c = (double)C[q]; csum += c * c; }
  double cn = sqrt(csum); if (cn < 1e-12) cn = 1e-12;
  const double a4 = 6.25e-6;                         // (STEP/2)^4
  const double coef = 1.4142135623730951 * a4 * ((double)C[f] / cn);
  const float  bf = (float)((double)f * 0.1);

  // --- runtime D-layout probe (layout-proof; verified R6/R7) ---
  int rIdx[4], cIdx[4];
  {
    d4 z = {0.0, 0.0, 0.0, 0.0};
    d4 pr = __builtin_amdgcn_mfma_f64_16x16x4f64((double)m, 1.0, z, 0, 0, 0);
    d4 pc = __builtin_amdgcn_mfma_f64_16x16x4f64(1.0, (double)m, z, 0, 0, 0);
#pragma unroll
    for (int r = 0; r < 4; ++r) {
      rIdx[r] = ((int)(pr[r] * 0.25 + 0.5)) & 15;
      cIdx[r] = ((int)(pc[r] * 0.25 + 0.5)) & 15;
    }
  }

  // phase 1: M = L - b I  (f32 LDS)
  const float* Lg = L + (size_t)g * NN * NN;
  for (int e = tid; e < NN * NN; e += 512) {
    int i = e >> 7, j = e & 127;
    float v = Lg[e];
    if (i == j) v -= bf;
    smf[i * SM + j] = v;
  }
  __syncthreads();

  // phase 2: P2 = M @ M  (fp32 VALU, 4x8 regs/thread; proven R3-R7)
  {
    const int tr = tid >> 4;                // 0..31
    const int tc = tid & 15;
    float p2r[4][8];
#pragma unroll
    for (int v = 0; v < 4; ++v)
#pragma unroll
      for (int u = 0; u < 8; ++u) p2r[v][u] = 0.f;
    for (int k = 0; k < NN; ++k) {
      float av[4], bv[8];
#pragma unroll
      for (int v = 0; v < 4; ++v) av[v] = smf[(4 * tr + v) * SM + k];
#pragma unroll
      for (int u = 0; u < 8; ++u) bv[u] = smf[k * SM + tc + 16 * u];
#pragma unroll
      for (int v = 0; v < 4; ++v)
#pragma unroll
        for (int u = 0; u < 8; ++u) p2r[v][u] = fmaf(av[v], bv[u], p2r[v][u]);
    }
    __syncthreads();
#pragma unroll
    for (int v = 0; v < 4; ++v)
#pragma unroll
      for (int u = 0; u < 8; ++u) smf[(4 * tr + v) * SM + tc + 16 * u] = p2r[v][u];
    __syncthreads();
  }

  // phase 3: T[cb] = (P2 @ P2 + a I) row-band 16wv  -- stays in registers
  d4 T[8];
#pragma unroll
  for (int cb = 0; cb < 8; ++cb)
#pragma unroll
    for (int r = 0; r < 4; ++r)
      T[cb][r] = ((16 * wv + rIdx[r]) == (16 * cb + cIdx[r])) ? a4 : 0.0;
  for (int kc = 0; kc < 32; ++kc) {
    double a = (double)smf[(16 * wv + m) * SM + 4 * kc + kq];
#pragma unroll
    for (int cb = 0; cb < 8; ++cb) {
      double b = (double)smf[(4 * kc + kq) * SM + 16 * cb + m];
      T[cb] = __builtin_amdgcn_mfma_f64_16x16x4f64(a, b, T[cb], 0, 0, 0);
    }
  }
  __syncthreads();   // P2 reads done; f32 region dead -> Rp/Sc alias it

  // phase 4: blocked GJ, 8 steps, 2 block-barriers each, NOT unrolled
#pragma unroll 1
  for (int t = 0; t < 8; ++t) {
    // publish row panel (wave t's OLD band, D-layout scatter)
    if (wv == t) {
#pragma unroll
      for (int cb = 0; cb < 8; ++cb)
#pragma unroll
        for (int r = 0; r < 4; ++r)
          Rp[rIdx[r] * RS + 16 * cb + cIdx[r]] = T[cb][r];
    }
    __syncthreads();                                 // B1

    // all waves redundantly: Pi = inv(A[K][K]), TRANSPOSED reg layout:
    // sr[r] on lane (kq,m) = A[4r+kq][m]
    double sr[4];
#pragma unroll
    for (int r = 0; r < 4; ++r) sr[r] = Rp[(4 * r + kq) * RS + 16 * t + m];
#pragma unroll
    for (int k = 0; k < 16; ++k) {
      const int kr = k >> 2, kl = k & 3;             // reg, quad of pivot row
      double pv   = __shfl(sr[kr], 16 * kl + k);     // A[k][k]
      double rowv = __shfl(sr[kr], 16 * kl + m);     // A[k][m]
      double cv[4];
#pragma unroll
      for (int r = 0; r < 4; ++r) cv[r] = __shfl(sr[r], 16 * kq + k);  // A[4r+kq][k]
      double dp = 1.0 / pv;
#pragma unroll
      for (int r = 0; r < 4; ++r) {
        int i = 4 * r + kq;
        double nv;
        if (i == k)      nv = (m == k) ? dp : rowv * dp;
        else if (m == k) nv = -cv[r] * dp;
        else             nv = fma(-(cv[r] * dp), rowv, sr[r]);
        sr[r] = nv;
      }
    }
    // sr[kc] is exactly the B-operand fragment of Pi for MFMA #kc

    // (c) column tile K: guarded unrolled loop keeps T indices STATIC
#pragma unroll
    for (int cb = 0; cb < 8; ++cb) {
      if (cb != t) continue;
      if (wv == t) {
        // T[cb] := Pi (D-layout via scratch); S := Pi row-major (a-source)
#pragma unroll
        for (int r = 0; r < 4; ++r) S[(4 * r + kq) * SS + m] = sr[r];
        __builtin_amdgcn_wave_barrier();
#pragma unroll
        for (int r = 0; r < 4; ++r) T[cb][r] = S[rIdx[r] * SS + cIdx[r]];
      } else {
        // scatter OLD tile -> S (row-major), then T[cb] := -(old @ Pi)
#pragma unroll
        for (int r = 0; r < 4; ++r) S[rIdx[r] * SS + cIdx[r]] = T[cb][r];
        __builtin_amdgcn_wave_barrier();
        d4 ncv = {0.0, 0.0, 0.0, 0.0};
#pragma unroll
        for (int kc = 0; kc < 4; ++kc) {
          double a = S[m * SS + 4 * kc + kq];
          ncv = __builtin_amdgcn_mfma_f64_16x16x4f64(a, -sr[kc], ncv, 0, 0, 0);
        }
        T[cb] = ncv;
        __builtin_amdgcn_wave_barrier();
        // S := new column tile row-major (a-source for trailing)
#pragma unroll
        for (int r = 0; r < 4; ++r) S[rIdx[r] * SS + cIdx[r]] = T[cb][r];
      }
    }
    __builtin_amdgcn_wave_barrier();

    // (d)/(f) unified trailing: a from own S, b from Rp
#pragma unroll
    for (int cb = 0; cb < 8; ++cb) {
      if (cb == t) continue;
      d4 acc;
      if (wv == t) { acc[0] = 0.0; acc[1] = 0.0; acc[2] = 0.0; acc[3] = 0.0; }
      else         { acc = T[cb]; }
#pragma unroll
      for (int kc = 0; kc < 4; ++kc) {
        double a = S[m * SS + 4 * kc + kq];
        double b = Rp[(4 * kc + kq) * RS + 16 * cb + m];
        acc = __builtin_amdgcn_mfma_f64_16x16x4f64(a, b, acc, 0, 0, 0);
      }
      T[cb] = acc;
    }
    __syncthreads();                                 // B2
  }

  // phase 5: W += coef * K^{-1}
  float* Wg = W + (size_t)g * NN * NN;
#pragma unroll
  for (int cb = 0; cb < 8; ++cb)
#pragma unroll
    for (int r = 0; r < 4; ++r)
      atomicAdd(&Wg[(16 * wv + rIdx[r]) * NN + 16 * cb + cIdx[r]],
                (float)(coef * T[cb][r]));
}

// ---------------------------------------------------------------------------
// K3a: Y = X - W @ X  per (graph, d-chunk of 128); also per-chunk emb (col means)
// ---------------------------------------------------------------------------
__global__ __launch_bounds__(256, 2) void k3a_y(
    const float* __restrict__ x, const float* __restrict__ rs,
    const float* __restrict__ W, float* __restrict__ Y,
    float* __restrict__ emb, int F0, int R, int DTOT, int NCH,
    float rscale) {
  extern __shared__ float sm3[];
  float* ldsW = sm3;                 // 128*129
  float* ldsX = sm3 + NN * SM;       // 128*129
  const int bid = blockIdx.x;
  const int g = bid / NCH;
  const int c = bid % NCH;
  const int d0 = c * 128;
  const int tid = threadIdx.x, tr = tid >> 4, tc = tid & 15;

  const float* Wg = W + (size_t)g * NN * NN;
  for (int e = tid; e < NN * NN; e += 256) {
    int k = e >> 7, i = e & 127;
    ldsW[k * SM + i] = Wg[e];
  }
  const float* xg = x + (size_t)g * NN * F0;
  const float* rg = rs + (size_t)g * NN * R;
  for (int e = tid; e < NN * NN; e += 256) {
    int k = e >> 7, dl = e & 127;
    int d = d0 + dl;
    float v = 0.f;
    if (d < DTOT) v = (d < F0) ? xg[k * F0 + d] : rg[k * R + (d - F0)] * rscale;
    ldsX[k * SM + dl] = v;
  }
  __syncthreads();

  float acc[8][8];
#pragma unroll
  for (int v = 0; v < 8; ++v)
#pragma unroll
    for (int u = 0; u < 8; ++u) acc[v][u] = 0.f;
  for (int k = 0; k < NN; ++k) {
    float wvv[8], xv[8];
#pragma unroll
    for (int v = 0; v < 8; ++v) wvv[v] = ldsW[k * SM + 8 * tr + v];  // W symmetric
#pragma unroll
    for (int u = 0; u < 8; ++u) xv[u] = ldsX[k * SM + tc + 16 * u];
#pragma unroll
    for (int v = 0; v < 8; ++v)
#pragma unroll
      for (int u = 0; u < 8; ++u) acc[v][u] = fmaf(wvv[v], xv[u], acc[v][u]);
  }
  float* Yg = Y + (size_t)g * NN * 1152;
#pragma unroll
  for (int v = 0; v < 8; ++v)
#pragma unroll
    for (int u = 0; u < 8; ++u) {
      float yv = ldsX[(8 * tr + v) * SM + tc + 16 * u] - acc[v][u];
      acc[v][u] = yv;
      Yg[(8 * tr + v) * 1152 + d0 + tc + 16 * u] = yv;
    }
  __syncthreads();
  float* embp = ldsW;
#pragma unroll
  for (int u = 0; u < 8; ++u) {
    float s = 0.f;
#pragma unroll
    for (int v = 0; v < 8; ++v) s += acc[v][u];
    embp[tr * 128 + tc + 16 * u] = s;
  }
  __syncthreads();
  if (tid < 128) {
    int d = d0 + tid;
    if (d < DTOT) {
      float s = 0.f;
      for (int tt = 0; tt < 16; ++tt) s += embp[tt * 128 + tid];
      emb[(size_t)g * 1152 + d] = s * (1.f / 128.f);
    }
  }
}

// ---------------------------------------------------------------------------
// K3b: G += Ychunk @ Ychunk^T  per (graph, d-chunk), via transposed LDS tile
// ---------------------------------------------------------------------------
__global__ __launch_bounds__(256, 2) void k3b_gram(
    const float* __restrict__ Y, float* __restrict__ G,
    int DTOT, int NCH) {
  extern __shared__ float sm4[];     // Yt[128 d][132]
  const int STT = 132;
  const int bid = blockIdx.x;
  const int g = bid / NCH, c = bid % NCH, d0 = c * 128;
  const int tid = threadIdx.x, tr = tid >> 4, tc = tid & 15;
  const float* Yg = Y + (size_t)g * NN * 1152;
  for (int e = tid; e < NN * NN; e += 256) {
    int i = e >> 7, dl = e & 127;
    int d = d0 + dl;
    sm4[dl * STT + i] = (d < DTOT) ? Yg[i * 1152 + d] : 0.f;
  }
  __syncthreads();
  float gg[8][8];
#pragma unroll
  for (int v = 0; v < 8; ++v)
#pragma unroll
    for (int u = 0; u < 8; ++u) gg[v][u] = 0.f;
  for (int dl = 0; dl < 128; ++dl) {
    float av[8], bv[8];
#pragma unroll
    for (int v = 0; v < 8; ++v) av[v] = sm4[dl * STT + 8 * tr + v];
#pragma unroll
    for (int u = 0; u < 8; ++u) bv[u] = sm4[dl * STT + tc + 16 * u];
#pragma unroll
    for (int v = 0; v < 8; ++v)
#pragma unroll
      for (int u = 0; u < 8; ++u) gg[v][u] = fmaf(av[v], bv[u], gg[v][u]);
  }
  float* Gg = G + (size_t)g * NN * NN;
#pragma unroll
  for (int v = 0; v < 8; ++v)
#pragma unroll
    for (int u = 0; u < 8; ++u)
      atomicAdd(&Gg[(8 * tr + v) * NN + tc + 16 * u], gg[v][u]);
}

// ---------------------------------------------------------------------------
// K4: sp_g = -sum_ij |G_ij| / (n_i n_j) / N^2
// ---------------------------------------------------------------------------
__global__ __launch_bounds__(256) void k4_sp(const float* __restrict__ G,
                                             double* __restrict__ spt) {
  __shared__ float inr[NN];
  __shared__ double red[4];
  const int g = blockIdx.x, tid = threadIdx.x;
  const float* Gg = G + (size_t)g * NN * NN;
  if (tid < NN) {
    float n = sqrtf(fmaxf(Gg[tid * NN + tid], 0.f));
    inr[tid] = 1.f / fmaxf(n, 1e-12f);
  }
  __syncthreads();
  double s = 0.0;
  for (int e = tid; e < NN * NN; e += 256) {
    int i = e >> 7, j = e & 127;
    s += (double)(fabsf(Gg[e]) * inr[i] * inr[j]);
  }
  for (int off = 32; off; off >>= 1) s += __shfl_down(s, off);
  int wave = tid >> 6, lane = tid & 63;
  if (lane == 0) red[wave] = s;
  __syncthreads();
  if (tid == 0) spt[g] = -(red[0] + red[1] + red[2] + red[3]) / (double)(NN * NN);
}

// ---------------------------------------------------------------------------
// K5a: 64x64 pairwise-distance matrix over embeddings
// ---------------------------------------------------------------------------
__global__ __launch_bounds__(256) void k5a_cdist(const float* __restrict__ emb,
                                                 float* __restrict__ Dm, int DTOT) {
  __shared__ float red[4];
  const int i = blockIdx.x, tid = threadIdx.x;
  float ei[5];
#pragma unroll
  for (int s2 = 0; s2 < 5; ++s2) {
    int d = tid + 256 * s2;
    ei[s2] = (d < DTOT) ? emb[(size_t)i * 1152 + d] : 0.f;
  }
  for (int j = 0; j < 64; ++j) {
    float acc = 0.f;
#pragma unroll
    for (int s2 = 0; s2 < 5; ++s2) {
      int d = tid + 256 * s2;
      if (d < DTOT) {
        float df = ei[s2] - emb[(size_t)j * 1152 + d];
        acc = fmaf(df, df, acc);
      }
    }
    for (int off = 32; off; off >>= 1) acc += __shfl_down(acc, off);
    int wave = tid >> 6, lane = tid & 63;
    if (lane == 0) red[wave] = acc;
    __syncthreads();
    if (tid == 0) {
      float d2 = red[0] + red[1] + red[2] + red[3];
      Dm[i * 64 + j] = (d2 > 0.f) ? sqrtf(d2) : 0.f;
    }
    __syncthreads();
  }
}

// ---------------------------------------------------------------------------
// K5b: final scalar (single wave)
// ---------------------------------------------------------------------------
__global__ __launch_bounds__(64) void k5b_final(
    const float* __restrict__ Dm, const double* __restrict__ spt,
    const float* __restrict__ C, int NF,
    const int* __restrict__ ncls, float* __restrict__ out) {
  const int lane = threadIdx.x;
  const int nc = ncls[0];
  double spf = spt[lane] * exp(-((double)(64 - lane)) * log(64.0));
  for (int off = 32; off; off >>= 1) spf += __shfl_down(spf, off);

  double hl1 = 0.0, hl2 = 0.0;
  const double beta = 1.0 / (double)nc + 1e-13;
  for (int cc = 0; cc < nc; ++cc) {
    bool ip = (lane % nc) == cc;
    double ps = 0.0, ns = 0.0;
    for (int j = 0; j < 64; ++j) {
      double dv = (double)Dm[lane * 64 + j];
      bool jp = (j % nc) == cc;
      if (ip && jp) ps += dv;
      if (!ip && !jp) ns += dv;
    }
    for (int off = 32; off; off >>= 1) {
      ps += __shfl_down(ps, off);
      ns += __shfl_down(ns, off);
    }
    int npos = 0;
    for (int q = 0; q < 64; ++q) if (q % nc == cc) npos++;
    int nneg = 64 - npos;
    hl2 += ps / ((double)npos * (double)npos);
    hl1 += -(ns / ((double)nneg * (double)nneg)) / beta;
  }
  if (lane == 0) {
    double l1 = 0.0, l2 = 0.0;
    for (int q = 0; q < NF; ++q) { double cv = (double)C[q]; l1 += fabs(cv); l2 += cv * cv; }
    l2 = sqrt(l2); if (l2 < 1e-12) l2 = 1e-12;
    double dims = sqrt((double)NF);
    double sc = (dims - l1 / l2) / (dims - 1.0);
    out[0] = (float)(sc + hl2 + hl1 + spf);
  }
}

// ---------------------------------------------------------------------------
extern "C" void kernel_launch(void* const* d_in, const int* in_sizes, int n_in,
                              void* d_out, int out_size, void* d_ws, size_t ws_size,
                              hipStream_t stream) {
  (void)n_in; (void)out_size; (void)ws_size;
  const float* x    = (const float*)d_in[0];
  const float* rs   = (const float*)d_in[1];
  const float* C    = (const float*)d_in[2];
  const int*   esrc = (const int*)d_in[3];
  const int*   edst = (const int*)d_in[4];
  const int*   ncls = (const int*)d_in[5];
  float* out = (float*)d_out;

  const int F0   = in_sizes[0] / (64 * 128);
  const int R    = in_sizes[1] / (64 * 128);
  const int NF   = in_sizes[2];
  const int E    = in_sizes[3] / 64;
  const int DTOT = F0 + R;
  const int NCH  = (DTOT + 127) / 128;
  const float rscale = (float)(1.0 / sqrt((double)R));

  char* ws = (char*)d_ws;
  size_t off = 0;
  float*  L   = (float*)(ws + off);  off += (size_t)64 * NN * NN * 4;
  float*  W   = (float*)(ws + off);  off += (size_t)64 * NN * NN * 4;
  float*  Y   = (float*)(ws + off);  off += (size_t)64 * NN * 1152 * 4;
  float*  G   = (float*)(ws + off);  off += (size_t)64 * NN * NN * 4;
  float*  emb = (float*)(ws + off);  off += (size_t)64 * 1152 * 4;
  double* spt = (double*)(ws + off); off += (size_t)64 * 8;
  float*  Dm  = (float*)(ws + off);  off += (size_t)64 * 64 * 4;

  hipMemsetAsync(W, 0, (size_t)64 * NN * NN * 4, stream);
  hipMemsetAsync(G, 0, (size_t)64 * NN * NN * 4, stream);

  const int lds1  = (NN * SM + NN) * 4;       // 66560
  const int lds2  = NN * SM * 4;              // 66048 (phase1-3 f32; phase4 aliases 34KB)
  const int lds3a = (NN * SM) * 4 * 2;        // 132096
  const int lds3b = NN * 132 * 4;             // 67584
  hipFuncSetAttribute((const void*)k1_laplacian, hipFuncAttributeMaxDynamicSharedMemorySize, lds1);
  hipFuncSetAttribute((const void*)k2_filter,    hipFuncAttributeMaxDynamicSharedMemorySize, lds2);
  hipFuncSetAttribute((const void*)k3a_y,        hipFuncAttributeMaxDynamicSharedMemorySize, lds3a);
  hipFuncSetAttribute((const void*)k3b_gram,     hipFuncAttributeMaxDynamicSharedMemorySize, lds3b);

  k1_laplacian<<<64, 256, lds1, stream>>>(esrc, edst, E, L);
  k2_filter<<<64 * NF, 512, lds2, stream>>>(L, C, NF, W);
  k3a_y<<<64 * NCH, 256, lds3a, stream>>>(x, rs, W, Y, emb, F0, R, DTOT, NCH, rscale);
  k3b_gram<<<64 * NCH, 256, lds3b, stream>>>(Y, G, DTOT, NCH);
  k4_sp<<<64, 256, 0, stream>>>(G, spt);
  k5a_cdist<<<64, 256, 0, stream>>>(emb, Dm, DTOT);
  k5b_final<<<1, 64, 0, stream>>>(Dm, spt, C, NF, ncls, out);
}

// Round 9
// 883.061 us; speedup vs baseline: 1.3042x; 1.0640x over previous
//
#include <hip/hip_runtime.h>
#include <math.h>

#define NN 128
#define SM 129   // padded LDS stride for 128-wide f32 tiles
#define RS 132   // row-panel stride (doubles)
#define SS 17    // per-wave scratch stride (doubles)

typedef double d4 __attribute__((ext_vector_type(4)));

// ---------------------------------------------------------------------------
// K1: build symmetric-normalized Laplacian per graph
// ---------------------------------------------------------------------------
__global__ __launch_bounds__(256) void k1_laplacian(
    const int* __restrict__ src, const int* __restrict__ dst,
    int E, float* __restrict__ Lout) {
  extern __shared__ float sm1[];            // A[128*129] + dinv[128]
  float* A    = sm1;
  float* dinv = sm1 + NN * SM;
  const int g   = blockIdx.x;
  const int tid = threadIdx.x;

  for (int e = tid; e < NN * NN; e += 256) {
    int i = e >> 7, j = e & 127;
    A[i * SM + j] = 0.f;
  }
  __syncthreads();
  const int* s = src + (size_t)g * E;
  const int* d = dst + (size_t)g * E;
  for (int e = tid; e < E; e += 256) {
    int a = s[e], b = d[e];
    A[a * SM + b] = 1.f;     // benign races: all write 1.0
    A[b * SM + a] = 1.f;
  }
  __syncthreads();
  if (tid < NN) {
    float acc = 0.f;
    for (int j = 0; j < NN; ++j) acc += A[tid * SM + j];
    dinv[tid] = (acc > 0.f) ? (float)(1.0 / sqrt((double)acc)) : 0.f;
  }
  __syncthreads();
  float* Lg = Lout + (size_t)g * NN * NN;
  for (int e = tid; e < NN * NN; e += 256) {
    int i = e >> 7, j = e & 127;
    Lg[e] = ((i == j) ? 1.f : 0.f) - dinv[i] * dinv[j] * A[i * SM + j];
  }
}

// ---------------------------------------------------------------------------
// K2 (R9): fully-MFMA pipeline. R8 measured: MFMA-busy 151us (f64 MFMA ~64cyc
// => ~78TF), VALU-busy 190us mostly from the fp32 VALU P2 (4096 FMA/thread).
// R9 moves P2 onto the f64 MFMA pipe (same row-band pattern as P4; result
// rounded to f32 LDS exactly as before). MFMA/wave: 256(P2)+256(P4)+258(GJ).
// Everything else identical to R8 (spill-proof shape: t-loop not unrolled,
// static T indices, transposed-Pi shuffle inversion).
// ---------------------------------------------------------------------------
__global__ __launch_bounds__(512, 4) void k2_filter(
    const float* __restrict__ L, const float* __restrict__ C,
    int NF, float* __restrict__ W) {
  extern __shared__ char smraw[];
  float*  smf = (float*)smraw;                       // phase 1-3: M / P2
  double* Rp  = (double*)smraw;                      // phase 4: row panel 16x132
  double* Scd = (double*)(smraw + 16 * RS * 8);      // 8 wave scratches 16x17

  const int bid = blockIdx.x;
  const int g = bid / NF, f = bid % NF;
  const int tid = threadIdx.x;
  const int wv = tid >> 6, ln = tid & 63;
  const int m  = ln & 15, kq = ln >> 4;   // forced A/B operand coords
  double* S = Scd + wv * 16 * SS;         // own wave scratch

  double csum = 0.0;
  for (int q = 0; q < NF; ++q) { double c = (double)C[q]; csum += c * c; }
  double cn = sqrt(csum); if (cn < 1e-12) cn = 1e-12;
  const double a4 = 6.25e-6;                         // (STEP/2)^4
  const double coef = 1.4142135623730951 * a4 * ((double)C[f] / cn);
  const float  bf = (float)((double)f * 0.1);

  // --- runtime D-layout probe (layout-proof; verified R6-R8) ---
  int rIdx[4], cIdx[4];
  {
    d4 z = {0.0, 0.0, 0.0, 0.0};
    d4 pr = __builtin_amdgcn_mfma_f64_16x16x4f64((double)m, 1.0, z, 0, 0, 0);
    d4 pc = __builtin_amdgcn_mfma_f64_16x16x4f64(1.0, (double)m, z, 0, 0, 0);
#pragma unroll
    for (int r = 0; r < 4; ++r) {
      rIdx[r] = ((int)(pr[r] * 0.25 + 0.5)) & 15;
      cIdx[r] = ((int)(pc[r] * 0.25 + 0.5)) & 15;
    }
  }

  // phase 1: M = L - b I  (f32 LDS)
  const float* Lg = L + (size_t)g * NN * NN;
  for (int e = tid; e < NN * NN; e += 512) {
    int i = e >> 7, j = e & 127;
    float v = Lg[e];
    if (i == j) v -= bf;
    smf[i * SM + j] = v;
  }
  __syncthreads();

  // phase 2 (R9): P2 = M @ M via f64 MFMA, row-band 16wv per wave; store f32
  {
    d4 p2a[8];
#pragma unroll
    for (int cb = 0; cb < 8; ++cb) {
      p2a[cb][0] = 0.0; p2a[cb][1] = 0.0; p2a[cb][2] = 0.0; p2a[cb][3] = 0.0;
    }
    for (int kc = 0; kc < 32; ++kc) {
      double a = (double)smf[(16 * wv + m) * SM + 4 * kc + kq];
#pragma unroll
      for (int cb = 0; cb < 8; ++cb) {
        double b = (double)smf[(4 * kc + kq) * SM + 16 * cb + m];
        p2a[cb] = __builtin_amdgcn_mfma_f64_16x16x4f64(a, b, p2a[cb], 0, 0, 0);
      }
    }
    __syncthreads();   // all M reads done before overwrite
#pragma unroll
    for (int cb = 0; cb < 8; ++cb)
#pragma unroll
      for (int r = 0; r < 4; ++r)
        smf[(16 * wv + rIdx[r]) * SM + 16 * cb + cIdx[r]] = (float)p2a[cb][r];
    __syncthreads();
  }

  // phase 3: T[cb] = (P2 @ P2 + a I) row-band 16wv  -- stays in registers
  d4 T[8];
#pragma unroll
  for (int cb = 0; cb < 8; ++cb)
#pragma unroll
    for (int r = 0; r < 4; ++r)
      T[cb][r] = ((16 * wv + rIdx[r]) == (16 * cb + cIdx[r])) ? a4 : 0.0;
  for (int kc = 0; kc < 32; ++kc) {
    double a = (double)smf[(16 * wv + m) * SM + 4 * kc + kq];
#pragma unroll
    for (int cb = 0; cb < 8; ++cb) {
      double b = (double)smf[(4 * kc + kq) * SM + 16 * cb + m];
      T[cb] = __builtin_amdgcn_mfma_f64_16x16x4f64(a, b, T[cb], 0, 0, 0);
    }
  }
  __syncthreads();   // P2 reads done; f32 region dead -> Rp/Sc alias it

  // phase 4: blocked GJ, 8 steps, 2 block-barriers each, NOT unrolled
#pragma unroll 1
  for (int t = 0; t < 8; ++t) {
    // publish row panel (wave t's OLD band, D-layout scatter)
    if (wv == t) {
#pragma unroll
      for (int cb = 0; cb < 8; ++cb)
#pragma unroll
        for (int r = 0; r < 4; ++r)
          Rp[rIdx[r] * RS + 16 * cb + cIdx[r]] = T[cb][r];
    }
    __syncthreads();                                 // B1

    // all waves redundantly: Pi = inv(A[K][K]), TRANSPOSED reg layout:
    // sr[r] on lane (kq,m) = A[4r+kq][m]
    double sr[4];
#pragma unroll
    for (int r = 0; r < 4; ++r) sr[r] = Rp[(4 * r + kq) * RS + 16 * t + m];
#pragma unroll
    for (int k = 0; k < 16; ++k) {
      const int kr = k >> 2, kl = k & 3;             // reg, quad of pivot row
      double pv   = __shfl(sr[kr], 16 * kl + k);     // A[k][k]
      double rowv = __shfl(sr[kr], 16 * kl + m);     // A[k][m]
      double cv[4];
#pragma unroll
      for (int r = 0; r < 4; ++r) cv[r] = __shfl(sr[r], 16 * kq + k);  // A[4r+kq][k]
      double dp = 1.0 / pv;
#pragma unroll
      for (int r = 0; r < 4; ++r) {
        int i = 4 * r + kq;
        double nv;
        if (i == k)      nv = (m == k) ? dp : rowv * dp;
        else if (m == k) nv = -cv[r] * dp;
        else             nv = fma(-(cv[r] * dp), rowv, sr[r]);
        sr[r] = nv;
      }
    }
    // sr[kc] is exactly the B-operand fragment of Pi for MFMA #kc

    // (c) column tile K: guarded unrolled loop keeps T indices STATIC
#pragma unroll
    for (int cb = 0; cb < 8; ++cb) {
      if (cb != t) continue;
      if (wv == t) {
        // T[cb] := Pi (D-layout via scratch); S := Pi row-major (a-source)
#pragma unroll
        for (int r = 0; r < 4; ++r) S[(4 * r + kq) * SS + m] = sr[r];
        __builtin_amdgcn_wave_barrier();
#pragma unroll
        for (int r = 0; r < 4; ++r) T[cb][r] = S[rIdx[r] * SS + cIdx[r]];
      } else {
        // scatter OLD tile -> S (row-major), then T[cb] := -(old @ Pi)
#pragma unroll
        for (int r = 0; r < 4; ++r) S[rIdx[r] * SS + cIdx[r]] = T[cb][r];
        __builtin_amdgcn_wave_barrier();
        d4 ncv = {0.0, 0.0, 0.0, 0.0};
#pragma unroll
        for (int kc = 0; kc < 4; ++kc) {
          double a = S[m * SS + 4 * kc + kq];
          ncv = __builtin_amdgcn_mfma_f64_16x16x4f64(a, -sr[kc], ncv, 0, 0, 0);
        }
        T[cb] = ncv;
        __builtin_amdgcn_wave_barrier();
        // S := new column tile row-major (a-source for trailing)
#pragma unroll
        for (int r = 0; r < 4; ++r) S[rIdx[r] * SS + cIdx[r]] = T[cb][r];
      }
    }
    __builtin_amdgcn_wave_barrier();

    // (d)/(f) unified trailing: a from own S, b from Rp
#pragma unroll
    for (int cb = 0; cb < 8; ++cb) {
      if (cb == t) continue;
      d4 acc;
      if (wv == t) { acc[0] = 0.0; acc[1] = 0.0; acc[2] = 0.0; acc[3] = 0.0; }
      else         { acc = T[cb]; }
#pragma unroll
      for (int kc = 0; kc < 4; ++kc) {
        double a = S[m * SS + 4 * kc + kq];
        double b = Rp[(4 * kc + kq) * RS + 16 * cb + m];
        acc = __builtin_amdgcn_mfma_f64_16x16x4f64(a, b, acc, 0, 0, 0);
      }
      T[cb] = acc;
    }
    __syncthreads();                                 // B2
  }

  // phase 5: W += coef * K^{-1}
  float* Wg = W + (size_t)g * NN * NN;
#pragma unroll
  for (int cb = 0; cb < 8; ++cb)
#pragma unroll
    for (int r = 0; r < 4; ++r)
      atomicAdd(&Wg[(16 * wv + rIdx[r]) * NN + 16 * cb + cIdx[r]],
                (float)(coef * T[cb][r]));
}

// ---------------------------------------------------------------------------
// K3 (R9 fused): per (graph, d-chunk): y = x - W@x, then IN-BLOCK transpose
// + Gram accumulation into G + emb column means. Y never touches HBM
// (removes 36MB write + 36MB read and one dispatch vs R8's k3a+k3b).
// ---------------------------------------------------------------------------
__global__ __launch_bounds__(256, 2) void k3_fused(
    const float* __restrict__ x, const float* __restrict__ rs,
    const float* __restrict__ W, float* __restrict__ G,
    float* __restrict__ emb, int F0, int R, int DTOT, int NCH,
    float rscale) {
  extern __shared__ float sm3[];
  float* ldsW = sm3;                 // 128*129, later yT
  float* ldsX = sm3 + NN * SM;       // 128*129, later emb partials
  const int bid = blockIdx.x;
  const int g = bid / NCH;
  const int c = bid % NCH;
  const int d0 = c * 128;
  const int tid = threadIdx.x, tr = tid >> 4, tc = tid & 15;

  const float* Wg = W + (size_t)g * NN * NN;
  for (int e = tid; e < NN * NN; e += 256) {
    int k = e >> 7, i = e & 127;
    ldsW[k * SM + i] = Wg[e];
  }
  const float* xg = x + (size_t)g * NN * F0;
  const float* rg = rs + (size_t)g * NN * R;
  for (int e = tid; e < NN * NN; e += 256) {
    int k = e >> 7, dl = e & 127;
    int d = d0 + dl;
    float v = 0.f;
    if (d < DTOT) v = (d < F0) ? xg[k * F0 + d] : rg[k * R + (d - F0)] * rscale;
    ldsX[k * SM + dl] = v;
  }
  __syncthreads();

  float acc[8][8];
#pragma unroll
  for (int v = 0; v < 8; ++v)
#pragma unroll
    for (int u = 0; u < 8; ++u) acc[v][u] = 0.f;
  for (int k = 0; k < NN; ++k) {
    float wvv[8], xv[8];
#pragma unroll
    for (int v = 0; v < 8; ++v) wvv[v] = ldsW[k * SM + 8 * tr + v];  // W symmetric
#pragma unroll
    for (int u = 0; u < 8; ++u) xv[u] = ldsX[k * SM + tc + 16 * u];
#pragma unroll
    for (int v = 0; v < 8; ++v)
#pragma unroll
      for (int u = 0; u < 8; ++u) acc[v][u] = fmaf(wvv[v], xv[u], acc[v][u]);
  }
  // y = x - acc (keep in regs)
#pragma unroll
  for (int v = 0; v < 8; ++v)
#pragma unroll
    for (int u = 0; u < 8; ++u)
      acc[v][u] = ldsX[(8 * tr + v) * SM + tc + 16 * u] - acc[v][u];
  __syncthreads();   // all ldsW/ldsX reads done -> reuse both regions

  // yT[d][i] into ldsW region; emb partials into ldsX region
#pragma unroll
  for (int v = 0; v < 8; ++v)
#pragma unroll
    for (int u = 0; u < 8; ++u)
      ldsW[(tc + 16 * u) * SM + 8 * tr + v] = acc[v][u];
#pragma unroll
  for (int u = 0; u < 8; ++u) {
    float s = 0.f;
#pragma unroll
    for (int v = 0; v < 8; ++v) s += acc[v][u];
    ldsX[tr * 128 + tc + 16 * u] = s;
  }
  __syncthreads();

  // Gram of the chunk: G += Yc @ Yc^T
  float gg[8][8];
#pragma unroll
  for (int v = 0; v < 8; ++v)
#pragma unroll
    for (int u = 0; u < 8; ++u) gg[v][u] = 0.f;
  for (int dl = 0; dl < NN; ++dl) {
    float av[8], bv[8];
#pragma unroll
    for (int v = 0; v < 8; ++v) av[v] = ldsW[dl * SM + 8 * tr + v];
#pragma unroll
    for (int u = 0; u < 8; ++u) bv[u] = ldsW[dl * SM + tc + 16 * u];
#pragma unroll
    for (int v = 0; v < 8; ++v)
#pragma unroll
      for (int u = 0; u < 8; ++u) gg[v][u] = fmaf(av[v], bv[u], gg[v][u]);
  }
  float* Gg = G + (size_t)g * NN * NN;
#pragma unroll
  for (int v = 0; v < 8; ++v)
#pragma unroll
    for (int u = 0; u < 8; ++u)
      atomicAdd(&Gg[(8 * tr + v) * NN + tc + 16 * u], gg[v][u]);

  if (tid < 128) {
    int d = d0 + tid;
    if (d < DTOT) {
      float s = 0.f;
      for (int tt = 0; tt < 16; ++tt) s += ldsX[tt * 128 + tid];
      emb[(size_t)g * 1152 + d] = s * (1.f / 128.f);
    }
  }
}

// ---------------------------------------------------------------------------
// K4: sp_g = -sum_ij |G_ij| / (n_i n_j) / N^2
// ---------------------------------------------------------------------------
__global__ __launch_bounds__(256) void k4_sp(const float* __restrict__ G,
                                             double* __restrict__ spt) {
  __shared__ float inr[NN];
  __shared__ double red[4];
  const int g = blockIdx.x, tid = threadIdx.x;
  const float* Gg = G + (size_t)g * NN * NN;
  if (tid < NN) {
    float n = sqrtf(fmaxf(Gg[tid * NN + tid], 0.f));
    inr[tid] = 1.f / fmaxf(n, 1e-12f);
  }
  __syncthreads();
  double s = 0.0;
  for (int e = tid; e < NN * NN; e += 256) {
    int i = e >> 7, j = e & 127;
    s += (double)(fabsf(Gg[e]) * inr[i] * inr[j]);
  }
  for (int off = 32; off; off >>= 1) s += __shfl_down(s, off);
  int wave = tid >> 6, lane = tid & 63;
  if (lane == 0) red[wave] = s;
  __syncthreads();
  if (tid == 0) spt[g] = -(red[0] + red[1] + red[2] + red[3]) / (double)(NN * NN);
}

// ---------------------------------------------------------------------------
// K5a (R9): barrier-free cdist. Wave w of block i handles j = 4*jj + w;
// per-wave 18-chunk dot (64 lanes x 18 = 1152) + shuffle reduction.
// ---------------------------------------------------------------------------
__global__ __launch_bounds__(256) void k5a_cdist(const float* __restrict__ emb,
                                                 float* __restrict__ Dm, int DTOT) {
  const int i = blockIdx.x;
  const int wv = threadIdx.x >> 6, l = threadIdx.x & 63;
  float ei[18];
#pragma unroll
  for (int s = 0; s < 18; ++s) {
    int d = l + 64 * s;
    ei[s] = (d < DTOT) ? emb[(size_t)i * 1152 + d] : 0.f;
  }
  for (int jj = 0; jj < 16; ++jj) {
    int j = 4 * jj + wv;
    float acc = 0.f;
#pragma unroll
    for (int s = 0; s < 18; ++s) {
      int d = l + 64 * s;
      if (d < DTOT) {
        float df = ei[s] - emb[(size_t)j * 1152 + d];
        acc = fmaf(df, df, acc);
      }
    }
    for (int off = 32; off; off >>= 1) acc += __shfl_down(acc, off);
    if (l == 0) Dm[i * 64 + j] = (acc > 0.f) ? sqrtf(acc) : 0.f;
  }
}

// ---------------------------------------------------------------------------
// K5b: final scalar (single wave)
// ---------------------------------------------------------------------------
__global__ __launch_bounds__(64) void k5b_final(
    const float* __restrict__ Dm, const double* __restrict__ spt,
    const float* __restrict__ C, int NF,
    const int* __restrict__ ncls, float* __restrict__ out) {
  const int lane = threadIdx.x;
  const int nc = ncls[0];
  double spf = spt[lane] * exp(-((double)(64 - lane)) * log(64.0));
  for (int off = 32; off; off >>= 1) spf += __shfl_down(spf, off);

  double hl1 = 0.0, hl2 = 0.0;
  const double beta = 1.0 / (double)nc + 1e-13;
  for (int cc = 0; cc < nc; ++cc) {
    bool ip = (lane % nc) == cc;
    double ps = 0.0, ns = 0.0;
    for (int j = 0; j < 64; ++j) {
      double dv = (double)Dm[lane * 64 + j];
      bool jp = (j % nc) == cc;
      if (ip && jp) ps += dv;
      if (!ip && !jp) ns += dv;
    }
    for (int off = 32; off; off >>= 1) {
      ps += __shfl_down(ps, off);
      ns += __shfl_down(ns, off);
    }
    int npos = 0;
    for (int q = 0; q < 64; ++q) if (q % nc == cc) npos++;
    int nneg = 64 - npos;
    hl2 += ps / ((double)npos * (double)npos);
    hl1 += -(ns / ((double)nneg * (double)nneg)) / beta;
  }
  if (lane == 0) {
    double l1 = 0.0, l2 = 0.0;
    for (int q = 0; q < NF; ++q) { double cv = (double)C[q]; l1 += fabs(cv); l2 += cv * cv; }
    l2 = sqrt(l2); if (l2 < 1e-12) l2 = 1e-12;
    double dims = sqrt((double)NF);
    double sc = (dims - l1 / l2) / (dims - 1.0);
    out[0] = (float)(sc + hl2 + hl1 + spf);
  }
}

// ---------------------------------------------------------------------------
extern "C" void kernel_launch(void* const* d_in, const int* in_sizes, int n_in,
                              void* d_out, int out_size, void* d_ws, size_t ws_size,
                              hipStream_t stream) {
  (void)n_in; (void)out_size; (void)ws_size;
  const float* x    = (const float*)d_in[0];
  const float* rs   = (const float*)d_in[1];
  const float* C    = (const float*)d_in[2];
  const int*   esrc = (const int*)d_in[3];
  const int*   edst = (const int*)d_in[4];
  const int*   ncls = (const int*)d_in[5];
  float* out = (float*)d_out;

  const int F0   = in_sizes[0] / (64 * 128);
  const int R    = in_sizes[1] / (64 * 128);
  const int NF   = in_sizes[2];
  const int E    = in_sizes[3] / 64;
  const int DTOT = F0 + R;
  const int NCH  = (DTOT + 127) / 128;
  const float rscale = (float)(1.0 / sqrt((double)R));

  char* ws = (char*)d_ws;
  size_t off = 0;
  float*  L   = (float*)(ws + off);  off += (size_t)64 * NN * NN * 4;
  float*  W   = (float*)(ws + off);  off += (size_t)64 * NN * NN * 4;
  float*  G   = (float*)(ws + off);  off += (size_t)64 * NN * NN * 4;
  float*  emb = (float*)(ws + off);  off += (size_t)64 * 1152 * 4;
  double* spt = (double*)(ws + off); off += (size_t)64 * 8;
  float*  Dm  = (float*)(ws + off);  off += (size_t)64 * 64 * 4;

  hipMemsetAsync(W, 0, (size_t)64 * NN * NN * 4, stream);
  hipMemsetAsync(G, 0, (size_t)64 * NN * NN * 4, stream);

  const int lds1 = (NN * SM + NN) * 4;       // 66560
  const int lds2 = NN * SM * 4;              // 66048
  const int lds3 = (NN * SM) * 4 * 2;        // 132096
  hipFuncSetAttribute((const void*)k1_laplacian, hipFuncAttributeMaxDynamicSharedMemorySize, lds1);
  hipFuncSetAttribute((const void*)k2_filter,    hipFuncAttributeMaxDynamicSharedMemorySize, lds2);
  hipFuncSetAttribute((const void*)k3_fused,     hipFuncAttributeMaxDynamicSharedMemorySize, lds3);

  k1_laplacian<<<64, 256, lds1, stream>>>(esrc, edst, E, L);
  k2_filter<<<64 * NF, 512, lds2, stream>>>(L, C, NF, W);
  k3_fused<<<64 * NCH, 256, lds3, stream>>>(x, rs, W, G, emb, F0, R, DTOT, NCH, rscale);
  k4_sp<<<64, 256, 0, stream>>>(G, spt);
  k5a_cdist<<<64, 256, 0, stream>>>(emb, Dm, DTOT);
  k5b_final<<<1, 64, 0, stream>>>(Dm, spt, C, NF, ncls, out);
}